// Round 1
// baseline (277.411 us; speedup 1.0000x reference)
//
#include <hip/hip_runtime.h>
#include <hip/hip_bf16.h>

#define NB 16
#define NL 8192
#define ND 256

#define KSPLIT 8
#define BK 64
#define KSTRIDE 72   // bf16 elems per LDS column; 144 B -> 16B aligned, uniform bank spread

typedef __bf16 bf16_t;
typedef __attribute__((ext_vector_type(8))) __bf16 bf16x8;
typedef __attribute__((ext_vector_type(4))) float floatx4;

// K1: per-row L2 norm -> e_l = exp(norm). One wave per row-group; lane i holds 4 cols.
__global__ __launch_bounds__(256) void k_norm_exp(const float* __restrict__ x,
                                                  float* __restrict__ e) {
    const int lane = threadIdx.x & 63;
    const int wave = threadIdx.x >> 6;
    const int row0 = blockIdx.x * 128 + wave * 32;
    #pragma unroll 4
    for (int i = 0; i < 32; ++i) {
        const int r = row0 + i;
        float4 v = *(const float4*)(x + (size_t)r * ND + lane * 4);
        float ss = v.x * v.x + v.y * v.y + v.z * v.z + v.w * v.w;
        #pragma unroll
        for (int off = 32; off; off >>= 1) ss += __shfl_xor(ss, off, 64);
        if (lane == 0) e[r] = __expf(sqrtf(ss));
    }
}

// K2: per batch: Z = sum(e); e_l <- sqrt(e_l / Z)  (= sqrt(softmax weight))
__global__ __launch_bounds__(256) void k_softmax_scale(float* __restrict__ e) {
    const int b = blockIdx.x;
    float* eb = e + b * NL;
    const int t = threadIdx.x;
    float vals[32];
    float sum = 0.f;
    #pragma unroll
    for (int i = 0; i < 32; ++i) { vals[i] = eb[t + i * 256]; sum += vals[i]; }
    #pragma unroll
    for (int off = 32; off; off >>= 1) sum += __shfl_xor(sum, off, 64);
    __shared__ float red[4];
    if ((t & 63) == 0) red[t >> 6] = sum;
    __syncthreads();
    const float rz = 1.0f / (red[0] + red[1] + red[2] + red[3]);
    #pragma unroll
    for (int i = 0; i < 32; ++i) eb[t + i * 256] = sqrtf(vals[i] * rz);
}

// K3: per batch, out = Y^T Y with Y = diag(s) X, bf16 MFMA.
// blockIdx: x = k-split chunk, y = tile-pair tp {0:(0,0), 1:(0,1), 2:(1,1)}, z = batch.
// 128x128 output tile per block, 4 waves, wave w owns row-tiles {2w,2w+1} x 8 col-tiles.
__global__ __launch_bounds__(256) void k_gemm(const float* __restrict__ x,
                                              const float* __restrict__ s,
                                              float* __restrict__ out) {
    const int ks = blockIdx.x;
    const int tp = blockIdx.y;
    const int b  = blockIdx.z;
    const int t = threadIdx.x;
    const int wave = t >> 6, lane = t & 63;

    const int col_off = (tp == 2) ? 128 : 0;   // global col of LDS col 0
    const int cpshift = (tp == 1) ? 7 : 6;     // log2(ncol/2)
    const int nunits  = (tp == 1) ? 4 : 2;     // staging units per thread
    const int bcol    = (tp == 1) ? 128 : 0;   // B-operand base col in LDS

    __shared__ bf16_t lds[256 * KSTRIDE];      // [col][k], transposed tile

    const float* xb = x + (size_t)b * NL * ND;
    const float* sb = s + b * NL;
    const int l0 = ks * (NL / KSPLIT);

    floatx4 acc[2][8];
    #pragma unroll
    for (int rt = 0; rt < 2; ++rt)
        #pragma unroll
        for (int ct = 0; ct < 8; ++ct)
            #pragma unroll
            for (int r = 0; r < 4; ++r) acc[rt][ct][r] = 0.f;

    for (int kk = 0; kk < NL / KSPLIT; kk += BK) {
        __syncthreads();
        // stage BK rows x ncol cols: load fp32 rows coalesced (float2/lane),
        // scale by s, convert bf16, write transposed as ds_write_b128 (8 k's per col).
        for (int i = 0; i < nunits; ++i) {
            const int u  = t + i * 256;
            const int cp = u & ((1 << cpshift) - 1);
            const int rg = u >> cpshift;            // 0..7 row-group of 8
            const int lrow = l0 + kk + rg * 8;
            bf16x8 p0, p1;
            #pragma unroll
            for (int j = 0; j < 8; ++j) {
                const int l = lrow + j;
                float2 v = *(const float2*)(xb + (size_t)l * ND + col_off + cp * 2);
                const float sc = sb[l];
                p0[j] = (bf16_t)(v.x * sc);
                p1[j] = (bf16_t)(v.y * sc);
            }
            *(bf16x8*)(lds + (2 * cp    ) * KSTRIDE + rg * 8) = p0;
            *(bf16x8*)(lds + (2 * cp + 1) * KSTRIDE + rg * 8) = p1;
        }
        __syncthreads();
        #pragma unroll
        for (int k2 = 0; k2 < 2; ++k2) {
            const int koff = k2 * 32 + (lane >> 4) * 8;
            bf16x8 af[2], bfr[8];
            #pragma unroll
            for (int rt = 0; rt < 2; ++rt) {
                const int col = (wave * 2 + rt) * 16 + (lane & 15);
                af[rt] = *(const bf16x8*)(lds + col * KSTRIDE + koff);
            }
            #pragma unroll
            for (int ct = 0; ct < 8; ++ct) {
                const int col = bcol + ct * 16 + (lane & 15);
                bfr[ct] = *(const bf16x8*)(lds + col * KSTRIDE + koff);
            }
            #pragma unroll
            for (int rt = 0; rt < 2; ++rt)
                #pragma unroll
                for (int ct = 0; ct < 8; ++ct)
                    acc[rt][ct] = __builtin_amdgcn_mfma_f32_16x16x32_bf16(
                        af[rt], bfr[ct], acc[rt][ct], 0, 0, 0);
        }
    }

    // epilogue: C/D layout col=lane&15, row=(lane>>4)*4+reg (HW-verified)
    float* ob = out + (size_t)b * ND * ND;
    const int d_base = (tp == 2) ? 128 : 0;
    const int e_base = (tp == 0) ? 0 : 128;
    #pragma unroll
    for (int rt = 0; rt < 2; ++rt) {
        const int d0 = d_base + (wave * 2 + rt) * 16 + (lane >> 4) * 4;
        #pragma unroll
        for (int ct = 0; ct < 8; ++ct) {
            const int e = e_base + ct * 16 + (lane & 15);
            #pragma unroll
            for (int reg = 0; reg < 4; ++reg) {
                const float v = acc[rt][ct][reg];
                atomicAdd(ob + (size_t)(d0 + reg) * ND + e, v);
                if (tp == 1) atomicAdd(ob + (size_t)e * ND + (d0 + reg), v);
            }
        }
    }
}

extern "C" void kernel_launch(void* const* d_in, const int* in_sizes, int n_in,
                              void* d_out, int out_size, void* d_ws, size_t ws_size,
                              hipStream_t stream) {
    const float* x = (const float*)d_in[0];
    float* out = (float*)d_out;
    float* e = (float*)d_ws;   // B*L floats = 512 KB scratch

    hipMemsetAsync(d_out, 0, (size_t)out_size * sizeof(float), stream);
    k_norm_exp<<<dim3(NB * NL / 128), 256, 0, stream>>>(x, e);
    k_softmax_scale<<<dim3(NB), 256, 0, stream>>>(e);
    k_gemm<<<dim3(KSPLIT, 3, NB), 256, 0, stream>>>(x, e, out);
}

// Round 2
// 260.233 us; speedup vs baseline: 1.0660x; 1.0660x over previous
//
#include <hip/hip_runtime.h>
#include <hip/hip_bf16.h>

#define NB 16
#define NL 8192
#define ND 256

#define KSPLIT 16
#define BK 64
#define KSTRIDE 72   // bf16 elems per LDS column; 144 B -> 16B aligned, read stride 4 banks/col

typedef __bf16 bf16_t;
typedef __attribute__((ext_vector_type(8))) __bf16 bf16x8;
typedef __attribute__((ext_vector_type(4))) float floatx4;

// K1: per-row L2 norm -> e_l = exp(norm).
// 4 rows per wave concurrently, 16 lanes per row (4 float4 loads each) -> 16
// independent loads in flight per wave-iteration, 1 shuffle-level/row.
__global__ __launch_bounds__(256) void k_norm_exp(const float* __restrict__ x,
                                                  float* __restrict__ e) {
    const int lane = threadIdx.x & 63;
    const int wave = threadIdx.x >> 6;
    const int sub  = lane >> 4;     // row within 4-row group
    const int c16  = lane & 15;
    const int row0 = blockIdx.x * 128 + wave * 32;
    #pragma unroll 2
    for (int i = 0; i < 8; ++i) {
        const int r = row0 + i * 4 + sub;
        const float* rp = x + (size_t)r * ND + c16 * 4;
        float ss = 0.f;
        #pragma unroll
        for (int q = 0; q < 4; ++q) {
            float4 v = *(const float4*)(rp + q * 64);
            ss += v.x * v.x + v.y * v.y + v.z * v.z + v.w * v.w;
        }
        #pragma unroll
        for (int off = 8; off; off >>= 1) ss += __shfl_xor(ss, off, 64);
        if (c16 == 0) e[r] = __expf(sqrtf(ss));
    }
}

// K2: per batch: Z = sum(e); e_l <- sqrt(e_l / Z)  (= sqrt(softmax weight))
__global__ __launch_bounds__(1024) void k_softmax_scale(float* __restrict__ e) {
    const int b = blockIdx.x;
    float* eb = e + b * NL;
    const int t = threadIdx.x;
    float vals[8];
    float sum = 0.f;
    #pragma unroll
    for (int i = 0; i < 8; ++i) { vals[i] = eb[t + i * 1024]; sum += vals[i]; }
    #pragma unroll
    for (int off = 32; off; off >>= 1) sum += __shfl_xor(sum, off, 64);
    __shared__ float red[16];
    if ((t & 63) == 0) red[t >> 6] = sum;
    __syncthreads();
    float z = 0.f;
    #pragma unroll
    for (int i = 0; i < 16; ++i) z += red[i];
    const float rz = 1.0f / z;
    #pragma unroll
    for (int i = 0; i < 8; ++i) eb[t + i * 1024] = sqrtf(vals[i] * rz);
}

// K3: per batch, out = Y^T Y with Y = diag(s) X, bf16 MFMA.
// blockIdx: x = k-split chunk, y = tile-pair tp {0:(0,0), 1:(0,1), 2:(1,1)}, z = batch.
// 128x128 output tile per block, 4 waves, wave w owns row-tiles {2w,2w+1} x 8 col-tiles.
__global__ __launch_bounds__(256) void k_gemm(const float* __restrict__ x,
                                              const float* __restrict__ s,
                                              float* __restrict__ out) {
    const int ks = blockIdx.x;
    const int tp = blockIdx.y;
    const int b  = blockIdx.z;
    const int t = threadIdx.x;
    const int wave = t >> 6, lane = t & 63;

    const int col_off = (tp == 2) ? 128 : 0;   // global col of LDS col 0
    const int cpshift = (tp == 1) ? 7 : 6;     // log2(ncol/2)
    const int nunits  = (tp == 1) ? 4 : 2;     // staging units per thread
    const int bcol    = (tp == 1) ? 128 : 0;   // B-operand base col in LDS

    __shared__ bf16_t lds[256 * KSTRIDE];      // [col][k], transposed tile

    const float* xb = x + (size_t)b * NL * ND;
    const float* sb = s + b * NL;
    const int l0 = ks * (NL / KSPLIT);

    floatx4 acc[2][8];
    #pragma unroll
    for (int rt = 0; rt < 2; ++rt)
        #pragma unroll
        for (int ct = 0; ct < 8; ++ct)
            #pragma unroll
            for (int r = 0; r < 4; ++r) acc[rt][ct][r] = 0.f;

    for (int kk = 0; kk < NL / KSPLIT; kk += BK) {
        __syncthreads();
        // stage BK rows x ncol cols: coalesced float2/lane fp32 loads,
        // scale by s, convert bf16, write transposed as ds_write_b128.
        for (int i = 0; i < nunits; ++i) {
            const int u  = t + i * 256;
            const int cp = u & ((1 << cpshift) - 1);
            const int rg = u >> cpshift;            // 0..7 row-group of 8
            const int lrow = l0 + kk + rg * 8;
            bf16x8 p0, p1;
            #pragma unroll
            for (int j = 0; j < 8; ++j) {
                const int l = lrow + j;
                float2 v = *(const float2*)(xb + (size_t)l * ND + col_off + cp * 2);
                const float sc = sb[l];
                p0[j] = (bf16_t)(v.x * sc);
                p1[j] = (bf16_t)(v.y * sc);
            }
            *(bf16x8*)(lds + (2 * cp    ) * KSTRIDE + rg * 8) = p0;
            *(bf16x8*)(lds + (2 * cp + 1) * KSTRIDE + rg * 8) = p1;
        }
        __syncthreads();
        #pragma unroll
        for (int k2 = 0; k2 < 2; ++k2) {
            const int koff = k2 * 32 + (lane >> 4) * 8;
            bf16x8 af[2], bfr[8];
            #pragma unroll
            for (int rt = 0; rt < 2; ++rt) {
                const int col = (wave * 2 + rt) * 16 + (lane & 15);
                af[rt] = *(const bf16x8*)(lds + col * KSTRIDE + koff);
            }
            #pragma unroll
            for (int ct = 0; ct < 8; ++ct) {
                const int col = bcol + ct * 16 + (lane & 15);
                bfr[ct] = *(const bf16x8*)(lds + col * KSTRIDE + koff);
            }
            #pragma unroll
            for (int rt = 0; rt < 2; ++rt)
                #pragma unroll
                for (int ct = 0; ct < 8; ++ct)
                    acc[rt][ct] = __builtin_amdgcn_mfma_f32_16x16x32_bf16(
                        af[rt], bfr[ct], acc[rt][ct], 0, 0, 0);
        }
    }

    // epilogue: C/D layout col=lane&15, row=(lane>>4)*4+reg (HW-verified)
    float* ob = out + (size_t)b * ND * ND;
    const int d_base = (tp == 2) ? 128 : 0;
    const int e_base = (tp == 0) ? 0 : 128;
    #pragma unroll
    for (int rt = 0; rt < 2; ++rt) {
        const int d0 = d_base + (wave * 2 + rt) * 16 + (lane >> 4) * 4;
        #pragma unroll
        for (int ct = 0; ct < 8; ++ct) {
            const int e = e_base + ct * 16 + (lane & 15);
            #pragma unroll
            for (int reg = 0; reg < 4; ++reg) {
                atomicAdd(ob + (size_t)(d0 + reg) * ND + e, acc[rt][ct][reg]);
            }
        }
    }
}

// K4: mirror the off-diagonal quadrant: out[b, 128:, :128] = out[b, :128, 128:]^T
__global__ __launch_bounds__(256) void k_mirror(float* __restrict__ out) {
    const int idx = blockIdx.x * 256 + threadIdx.x;
    const int b = idx >> 14;
    const int r = idx & 16383;
    const int d = r >> 7;            // 0..127
    const int e = 128 + (r & 127);   // 128..255
    float* ob = out + (size_t)b * ND * ND;
    ob[(size_t)e * ND + d] = ob[(size_t)d * ND + e];
}

extern "C" void kernel_launch(void* const* d_in, const int* in_sizes, int n_in,
                              void* d_out, int out_size, void* d_ws, size_t ws_size,
                              hipStream_t stream) {
    const float* x = (const float*)d_in[0];
    float* out = (float*)d_out;
    float* e = (float*)d_ws;   // B*L floats = 512 KB scratch

    hipMemsetAsync(d_out, 0, (size_t)out_size * sizeof(float), stream);
    k_norm_exp<<<dim3(NB * NL / 128), 256, 0, stream>>>(x, e);
    k_softmax_scale<<<dim3(NB), 1024, 0, stream>>>(e);
    k_gemm<<<dim3(KSPLIT, 3, NB), 256, 0, stream>>>(x, e, out);
    k_mirror<<<dim3(NB * 128 * 128 / 256), 256, 0, stream>>>(out);
}